// Round 1
// baseline (412.540 us; speedup 1.0000x reference)
//
#include <hip/hip_runtime.h>
#include <cstdint>

#define TT 50
#define II 5
#define PRED 12
#define SAMP 32     // samples per block
#define NSB 2       // 16-col MFMA tiles per step = SAMP/16

typedef _Float16 f16;
typedef _Float16 f16x8 __attribute__((ext_vector_type(8)));
typedef float f32x4 __attribute__((ext_vector_type(4)));

__device__ __forceinline__ float fsig(float x) {
    return __builtin_amdgcn_rcpf(1.f + __builtin_amdgcn_exp2f(-1.4426950408889634f * x));
}
__device__ __forceinline__ float ftanh(float x) {
    return 1.f - 2.f * __builtin_amdgcn_rcpf(1.f + __builtin_amdgcn_exp2f(2.885390081777927f * x));
}

// Build this lane's A-operand fragments for W_cat = [Whh | Wih | b | 0pad] (512 x 160).
// Fragment element j of (gs,kc) holds Wcat[g][k], g = gs*128 + w*16 + cl, k = kc*32 + q*8 + j.
// kc=4 (k=128..159): only q==0 lanes are nonzero (k=128..133 = Wih cols + bias), rest zero.
__device__ __forceinline__ void load_frags(const float* __restrict__ Wih,
                                           const float* __restrict__ Whh,
                                           const float* __restrict__ bih,
                                           const float* __restrict__ bhh,
                                           int w, int q, int cl, f16x8 wr[4][5]) {
    #pragma unroll
    for (int gs = 0; gs < 4; ++gs) {
        const int g = gs * 128 + w * 16 + cl;
        const float* whr = Whh + g * 128 + q * 8;
        #pragma unroll
        for (int kc = 0; kc < 4; ++kc) {
            f32x4 a = *(const f32x4*)(whr + kc * 32);
            f32x4 b = *(const f32x4*)(whr + kc * 32 + 4);
            f16x8 f;
            f[0] = (f16)a[0]; f[1] = (f16)a[1]; f[2] = (f16)a[2]; f[3] = (f16)a[3];
            f[4] = (f16)b[0]; f[5] = (f16)b[1]; f[6] = (f16)b[2]; f[7] = (f16)b[3];
            wr[gs][kc] = f;
        }
        f16x8 f;
        #pragma unroll
        for (int j = 0; j < 8; ++j) f[j] = (f16)0.f;
        if (q == 0) {
            f[0] = (f16)Wih[g * 5 + 0]; f[1] = (f16)Wih[g * 5 + 1];
            f[2] = (f16)Wih[g * 5 + 2]; f[3] = (f16)Wih[g * 5 + 3];
            f[4] = (f16)Wih[g * 5 + 4];
            f[5] = (f16)(bih[g] + bhh[g]);
        }
        wr[gs][4] = f;
    }
}

// 512 blocks x 512 threads; 32 samples/block -> 2 blocks/CU (needs VGPR<=128).
// State: double-buffered h rows, 256 B/row (16 chunks of 16 B), chunk swizzle
// phys = logical ^ (2*(row&7)). x / decoder-input staged once in xstage[52][32][8] f16.
// Encoder: ONE barrier per step (read buf[p], write buf[p^1]). Decoder: two (predpart).
__global__ __launch_bounds__(512, 4)
void lstm_kernel(const float* __restrict__ x,
                 const float* __restrict__ eWih, const float* __restrict__ eWhh,
                 const float* __restrict__ ebih, const float* __restrict__ ebhh,
                 const float* __restrict__ dWih, const float* __restrict__ dWhh,
                 const float* __restrict__ dbih, const float* __restrict__ dbhh,
                 const float* __restrict__ linW, const float* __restrict__ linB,
                 float* __restrict__ out) {
    __shared__ __align__(16) unsigned char state[2 * SAMP * 256];   // 16 KB
    __shared__ __align__(16) f16 xstage[52 * SAMP * 8];             // 26 KB: slots 0..49 = x(t); 50/51 = dec_in dbuf
    __shared__ float predpart[8][SAMP][2];

    const int tid  = threadIdx.x;
    const int lane = tid & 63;
    const int w    = tid >> 6;       // wave 0..7
    const int q    = lane >> 4;      // 0..3
    const int cl   = lane & 15;      // 0..15
    const int s0   = blockIdx.x * SAMP;
    const int jb   = w * 16 + q * 4;                    // this lane's hidden-j base
    const int physh = ((jb >> 3) ^ (2 * (cl & 7))) & 15;
    const int hoff  = (jb & 7) * 2;

    // per-lane LDS byte offsets (within one state buffer, before +ns*4096)
    int hro[4];
    #pragma unroll
    for (int kc = 0; kc < 4; ++kc)
        hro[kc] = cl * 256 + ((((kc * 4 + q) ^ (2 * (cl & 7))) & 15) << 4);
    const int hwo = cl * 256 + physh * 16 + hoff;

    // ---- init: zero both state buffers (h0 = 0), stage all x as f16 rows ----
    {
        uint32_t* sp = (uint32_t*)state;
        #pragma unroll
        for (int r = 0; r < 8; ++r) sp[tid + r * 512] = 0u;   // 16384 B
    }
    #pragma unroll
    for (int k = 0; k < 4; ++k) {
        int c = tid + k * 512;
        if (c < TT * SAMP) {
            int t = c >> 5, s = c & 31;
            const float* xr = x + (size_t)(s0 + s) * (TT * II) + t * II;
            union { f16 h[8]; uint4 u; } pk;
            pk.h[0] = (f16)xr[0]; pk.h[1] = (f16)xr[1]; pk.h[2] = (f16)xr[2];
            pk.h[3] = (f16)xr[3]; pk.h[4] = (f16)xr[4];
            pk.h[5] = (f16)1.f;  pk.h[6] = (f16)0.f;  pk.h[7] = (f16)0.f;
            *(uint4*)(xstage + (t * SAMP + s) * 8) = pk.u;
        }
    }

    // encoder weight fragments (from raw f32 weights; L2-resident, no prep kernel)
    f16x8 wr[4][5];
    load_frags(eWih, eWhh, ebih, ebhh, w, q, cl, wr);

    float creg[NSB][4];
    #pragma unroll
    for (int ns = 0; ns < NSB; ++ns)
        #pragma unroll
        for (int i = 0; i < 4; ++i) creg[ns][i] = 0.f;

    const f32x4 zero4 = {0.f, 0.f, 0.f, 0.f};
    __syncthreads();

    // ===================== encoder: 1 barrier/step =====================
    #pragma unroll 1
    for (int t = 0; t < TT; ++t) {
        const int curoff = (t & 1) << 13;        // *8192
        const int nxtoff = curoff ^ 8192;
        #pragma unroll
        for (int ns = 0; ns < NSB; ++ns) {
            const unsigned char* cb = state + curoff + ns * 4096;
            f16x8 bx = *(const f16x8*)(xstage + (t * SAMP + ns * 16 + cl) * 8);
            f16x8 b0 = *(const f16x8*)(cb + hro[0]);
            f32x4 a0 = __builtin_amdgcn_mfma_f32_16x16x32_f16(wr[0][0], b0, zero4, 0, 0, 0);
            f32x4 a1 = __builtin_amdgcn_mfma_f32_16x16x32_f16(wr[1][0], b0, zero4, 0, 0, 0);
            f32x4 a2 = __builtin_amdgcn_mfma_f32_16x16x32_f16(wr[2][0], b0, zero4, 0, 0, 0);
            f32x4 a3 = __builtin_amdgcn_mfma_f32_16x16x32_f16(wr[3][0], b0, zero4, 0, 0, 0);
            #pragma unroll
            for (int kc = 1; kc < 4; ++kc) {
                f16x8 bh = *(const f16x8*)(cb + hro[kc]);
                a0 = __builtin_amdgcn_mfma_f32_16x16x32_f16(wr[0][kc], bh, a0, 0, 0, 0);
                a1 = __builtin_amdgcn_mfma_f32_16x16x32_f16(wr[1][kc], bh, a1, 0, 0, 0);
                a2 = __builtin_amdgcn_mfma_f32_16x16x32_f16(wr[2][kc], bh, a2, 0, 0, 0);
                a3 = __builtin_amdgcn_mfma_f32_16x16x32_f16(wr[3][kc], bh, a3, 0, 0, 0);
            }
            a0 = __builtin_amdgcn_mfma_f32_16x16x32_f16(wr[0][4], bx, a0, 0, 0, 0);
            a1 = __builtin_amdgcn_mfma_f32_16x16x32_f16(wr[1][4], bx, a1, 0, 0, 0);
            a2 = __builtin_amdgcn_mfma_f32_16x16x32_f16(wr[2][4], bx, a2, 0, 0, 0);
            a3 = __builtin_amdgcn_mfma_f32_16x16x32_f16(wr[3][4], bx, a3, 0, 0, 0);

            union { f16 h[4]; uint2 u; } pk;
            #pragma unroll
            for (int idx = 0; idx < 4; ++idx) {
                float ii = fsig(a0[idx]);
                float ff = fsig(a1[idx]);
                float gg = ftanh(a2[idx]);
                float oo = fsig(a3[idx]);
                float cn = ff * creg[ns][idx] + ii * gg;
                creg[ns][idx] = cn;
                pk.h[idx] = (f16)(oo * ftanh(cn));
            }
            *(uint2*)(state + nxtoff + ns * 4096 + hwo) = pk.u;  // write to NEXT buffer
        }
        __syncthreads();   // writes to nxt visible; cur reads done
    }

    // decoder weight fragments + decoder-only registers (loaded late: keep encoder VGPR low)
    load_frags(dWih, dWhh, dbih, dbhh, w, q, cl, wr);
    float w0r[4], w1r[4];
    #pragma unroll
    for (int idx = 0; idx < 4; ++idx) {
        w0r[idx] = linW[jb + idx];
        w1r[idx] = linW[128 + jb + idx];
    }
    float sc0 = 0.f, sc1 = 0.f, sc2 = 0.f, lb0 = 0.f, lb1 = 0.f;
    if (tid < SAMP) {
        const float* xr = x + (size_t)(s0 + tid) * (TT * II) + 49 * II;
        sc0 = xr[2]; sc1 = xr[3]; sc2 = xr[4];
        lb0 = linB[0]; lb1 = linB[1];
    }

    // ===================== decoder =====================
    // after 50 encoder steps, h lives in buf0; dec_in0 = x[49] already in xstage slot 49
    #pragma unroll 1
    for (int td = 0; td < PRED; ++td) {
        const int curoff = (td & 1) << 13;
        const int nxtoff = curoff ^ 8192;
        const int xslot  = (td == 0) ? 49 : (50 + (td & 1));
        float p0s[NSB], p1s[NSB];
        #pragma unroll
        for (int ns = 0; ns < NSB; ++ns) {
            const unsigned char* cb = state + curoff + ns * 4096;
            f16x8 bx = *(const f16x8*)(xstage + (xslot * SAMP + ns * 16 + cl) * 8);
            f16x8 b0 = *(const f16x8*)(cb + hro[0]);
            f32x4 a0 = __builtin_amdgcn_mfma_f32_16x16x32_f16(wr[0][0], b0, zero4, 0, 0, 0);
            f32x4 a1 = __builtin_amdgcn_mfma_f32_16x16x32_f16(wr[1][0], b0, zero4, 0, 0, 0);
            f32x4 a2 = __builtin_amdgcn_mfma_f32_16x16x32_f16(wr[2][0], b0, zero4, 0, 0, 0);
            f32x4 a3 = __builtin_amdgcn_mfma_f32_16x16x32_f16(wr[3][0], b0, zero4, 0, 0, 0);
            #pragma unroll
            for (int kc = 1; kc < 4; ++kc) {
                f16x8 bh = *(const f16x8*)(cb + hro[kc]);
                a0 = __builtin_amdgcn_mfma_f32_16x16x32_f16(wr[0][kc], bh, a0, 0, 0, 0);
                a1 = __builtin_amdgcn_mfma_f32_16x16x32_f16(wr[1][kc], bh, a1, 0, 0, 0);
                a2 = __builtin_amdgcn_mfma_f32_16x16x32_f16(wr[2][kc], bh, a2, 0, 0, 0);
                a3 = __builtin_amdgcn_mfma_f32_16x16x32_f16(wr[3][kc], bh, a3, 0, 0, 0);
            }
            a0 = __builtin_amdgcn_mfma_f32_16x16x32_f16(wr[0][4], bx, a0, 0, 0, 0);
            a1 = __builtin_amdgcn_mfma_f32_16x16x32_f16(wr[1][4], bx, a1, 0, 0, 0);
            a2 = __builtin_amdgcn_mfma_f32_16x16x32_f16(wr[2][4], bx, a2, 0, 0, 0);
            a3 = __builtin_amdgcn_mfma_f32_16x16x32_f16(wr[3][4], bx, a3, 0, 0, 0);

            float p0 = 0.f, p1 = 0.f;
            union { f16 h[4]; uint2 u; } pk;
            #pragma unroll
            for (int idx = 0; idx < 4; ++idx) {
                float ii = fsig(a0[idx]);
                float ff = fsig(a1[idx]);
                float gg = ftanh(a2[idx]);
                float oo = fsig(a3[idx]);
                float cn = ff * creg[ns][idx] + ii * gg;
                creg[ns][idx] = cn;
                float hv = oo * ftanh(cn);
                p0 += hv * w0r[idx];
                p1 += hv * w1r[idx];
                pk.h[idx] = (f16)hv;
            }
            *(uint2*)(state + nxtoff + ns * 4096 + hwo) = pk.u;
            // reduce over q (lanes l, l^16, l^32, l^48 share sample column)
            p0 += __shfl_xor(p0, 16); p0 += __shfl_xor(p0, 32);
            p1 += __shfl_xor(p1, 16); p1 += __shfl_xor(p1, 32);
            p0s[ns] = p0; p1s[ns] = p1;
        }
        if (q == 0) {
            #pragma unroll
            for (int ns = 0; ns < NSB; ++ns) {
                predpart[w][ns * 16 + cl][0] = p0s[ns];
                predpart[w][ns * 16 + cl][1] = p1s[ns];
            }
        }
        __syncthreads();   // A: predpart ready, state reads done
        if (tid < SAMP) {
            float a0 = lb0, a1 = lb1;
            #pragma unroll
            for (int ww = 0; ww < 8; ++ww) {
                a0 += predpart[ww][tid][0];
                a1 += predpart[ww][tid][1];
            }
            float2 o2; o2.x = a0; o2.y = a1;
            *(float2*)(out + (size_t)(s0 + tid) * (PRED * 2) + td * 2) = o2;
            union { f16 h[8]; uint4 u; } pk;
            pk.h[0] = (f16)a0;  pk.h[1] = (f16)a1;
            pk.h[2] = (f16)sc0; pk.h[3] = (f16)sc1; pk.h[4] = (f16)sc2;
            pk.h[5] = (f16)1.f; pk.h[6] = (f16)0.f; pk.h[7] = (f16)0.f;
            int ws = 50 + ((td + 1) & 1);
            *(uint4*)(xstage + (ws * SAMP + tid) * 8) = pk.u;   // next dec_in
        }
        __syncthreads();   // B: dec_in visible
    }
}

extern "C" void kernel_launch(void* const* d_in, const int* in_sizes, int n_in,
                              void* d_out, int out_size, void* d_ws, size_t ws_size,
                              hipStream_t stream) {
    (void)in_sizes; (void)n_in; (void)out_size; (void)d_ws; (void)ws_size;
    const float* x    = (const float*)d_in[0];
    const float* eWih = (const float*)d_in[1];
    const float* eWhh = (const float*)d_in[2];
    const float* ebih = (const float*)d_in[3];
    const float* ebhh = (const float*)d_in[4];
    const float* dWih = (const float*)d_in[5];
    const float* dWhh = (const float*)d_in[6];
    const float* dbih = (const float*)d_in[7];
    const float* dbhh = (const float*)d_in[8];
    const float* linW = (const float*)d_in[9];
    const float* linB = (const float*)d_in[10];

    lstm_kernel<<<512, 512, 0, stream>>>(x, eWih, eWhh, ebih, ebhh,
                                         dWih, dWhh, dbih, dbhh,
                                         linW, linB, (float*)d_out);
}

// Round 2
// 283.970 us; speedup vs baseline: 1.4528x; 1.4528x over previous
//
#include <hip/hip_runtime.h>
#include <cstdint>

#define TT 50
#define II 5
#define PRED 12
#define SAMP 64     // samples per block
#define NSB 4       // 16-col MFMA tiles per step

typedef _Float16 f16;
typedef _Float16 f16x8 __attribute__((ext_vector_type(8)));
typedef float f32x4 __attribute__((ext_vector_type(4)));

__device__ __forceinline__ float fsig(float x) {
    return __builtin_amdgcn_rcpf(1.f + __builtin_amdgcn_exp2f(-1.4426950408889634f * x));
}
__device__ __forceinline__ float ftanh(float x) {
    return 1.f - 2.f * __builtin_amdgcn_rcpf(1.f + __builtin_amdgcn_exp2f(2.885390081777927f * x));
}

// A-fragments, unit-pair-interleaved row permutation.
// Tile (w,gs): tile-row r holds global gate-row gw = (r&3)*128 + w*8 + (r>>2)*2 + gs
//   (i.e., gate r&3 of hidden unit w*8 + (r>>2)*2 + gs).
// Lane (q,cl), element j of wr[gs][kc] = A[r=cl][k=kc*32+q*8+j]:
//   kc<4 -> Whh[gw][k];  kc=4 (only q==0 nonzero): j<5 Wih[gw][j], j==5 bih+bhh, else 0.
// MFMA C layout (col=lane&15, row=q*4+idx) then gives acc[gs][ns][idx] =
//   gate idx (i,f,g,o) of unit U = w*8 + q*2 + gs, sample S = ns*16 + cl.
__device__ __forceinline__ void load_frags(const float* __restrict__ Wih,
                                           const float* __restrict__ Whh,
                                           const float* __restrict__ bih,
                                           const float* __restrict__ bhh,
                                           int w, int q, int cl, f16x8 wr[2][5]) {
    #pragma unroll
    for (int gs = 0; gs < 2; ++gs) {
        const int gw = (cl & 3) * 128 + w * 8 + (cl >> 2) * 2 + gs;
        const float* whr = Whh + gw * 128 + q * 8;
        #pragma unroll
        for (int kc = 0; kc < 4; ++kc) {
            f32x4 a = *(const f32x4*)(whr + kc * 32);
            f32x4 b = *(const f32x4*)(whr + kc * 32 + 4);
            f16x8 f;
            f[0] = (f16)a[0]; f[1] = (f16)a[1]; f[2] = (f16)a[2]; f[3] = (f16)a[3];
            f[4] = (f16)b[0]; f[5] = (f16)b[1]; f[6] = (f16)b[2]; f[7] = (f16)b[3];
            wr[gs][kc] = f;
        }
        f16x8 f;
        #pragma unroll
        for (int j = 0; j < 8; ++j) f[j] = (f16)0.f;
        if (q == 0) {
            f[0] = (f16)Wih[gw * 5 + 0]; f[1] = (f16)Wih[gw * 5 + 1];
            f[2] = (f16)Wih[gw * 5 + 2]; f[3] = (f16)Wih[gw * 5 + 3];
            f[4] = (f16)Wih[gw * 5 + 4];
            f[5] = (f16)(bih[gw] + bhh[gw]);
        }
        wr[gs][4] = f;
    }
}

// 256 blocks x 1024 threads (16 waves = 4 waves/EU), 64 samples/block, 1 block/CU.
// Weight fragments: 40 VGPR/lane (vs 80 at 512 threads) -> fits the 128-VGPR cap.
// State: double-buffered h rows, 256 B/row (16 chunks of 16 B), chunk swizzle
// phys = chunk ^ fswz(row&15), fswz(c) = 2*(c&7) | (c>>3)  (bijective, even banks).
// Encoder: ONE barrier/step. Decoder: two (predpart reduction).
__global__ __launch_bounds__(1024, 1)
void lstm_kernel(const float* __restrict__ x,
                 const float* __restrict__ eWih, const float* __restrict__ eWhh,
                 const float* __restrict__ ebih, const float* __restrict__ ebhh,
                 const float* __restrict__ dWih, const float* __restrict__ dWhh,
                 const float* __restrict__ dbih, const float* __restrict__ dbhh,
                 const float* __restrict__ linW, const float* __restrict__ linB,
                 float* __restrict__ out) {
    __shared__ __align__(16) unsigned char state[2 * SAMP * 256];   // 32 KB
    __shared__ __align__(16) f16 xstage[52 * SAMP * 8];             // 53.25 KB
    __shared__ float predpart[16][SAMP][2];                         // 8 KB

    const int tid  = threadIdx.x;
    const int lane = tid & 63;
    const int w    = tid >> 6;       // wave 0..15
    const int q    = lane >> 4;      // 0..3
    const int cl   = lane & 15;      // 0..15
    const int s0   = blockIdx.x * SAMP;
    const int fswz = (2 * (cl & 7)) | (cl >> 3);     // bijective 0..15

    // per-lane LDS byte offsets (within one state buffer, before +ns*4096)
    int hro[4];
    #pragma unroll
    for (int kc = 0; kc < 4; ++kc)
        hro[kc] = cl * 256 + (((kc * 4 + q) ^ fswz) & 15) * 16;
    // h write: units w*8+q*2+{0,1} -> chunk w, dword q (both gs in one b32)
    const int hwo = cl * 256 + ((w ^ fswz) & 15) * 16 + q * 4;

    // ---- init: zero state buffer 0 (h0 = 0), stage all x as f16 rows ----
    {
        uint32_t* sp = (uint32_t*)state;
        #pragma unroll
        for (int r = 0; r < 4; ++r) sp[tid + r * 1024] = 0u;   // 16384 B = buffer 0
    }
    #pragma unroll
    for (int k = 0; k < 4; ++k) {
        int c = tid + k * 1024;
        if (c < TT * SAMP) {
            int t = c >> 6, s = c & 63;
            const float* xr = x + (size_t)(s0 + s) * (TT * II) + t * II;
            union { f16 h[8]; uint4 u; } pk;
            pk.h[0] = (f16)xr[0]; pk.h[1] = (f16)xr[1]; pk.h[2] = (f16)xr[2];
            pk.h[3] = (f16)xr[3]; pk.h[4] = (f16)xr[4];
            pk.h[5] = (f16)1.f;  pk.h[6] = (f16)0.f;  pk.h[7] = (f16)0.f;
            *(uint4*)(xstage + (t * SAMP + s) * 8) = pk.u;
        }
    }

    f16x8 wr[2][5];
    load_frags(eWih, eWhh, ebih, ebhh, w, q, cl, wr);

    float creg[2][NSB];
    #pragma unroll
    for (int gs = 0; gs < 2; ++gs)
        #pragma unroll
        for (int ns = 0; ns < NSB; ++ns) creg[gs][ns] = 0.f;

    const f32x4 zero4 = {0.f, 0.f, 0.f, 0.f};
    __syncthreads();

    // ===================== encoder: 1 barrier/step =====================
    #pragma unroll 1
    for (int t = 0; t < TT; ++t) {
        const int curoff = (t & 1) << 14;        // *16384
        const int nxtoff = curoff ^ 16384;
        #pragma unroll
        for (int ns = 0; ns < NSB; ++ns) {
            const unsigned char* cb = state + curoff + ns * 4096;
            f16x8 bx = *(const f16x8*)(xstage + (t * SAMP + ns * 16 + cl) * 8);
            f16x8 b0 = *(const f16x8*)(cb + hro[0]);
            f32x4 a0 = __builtin_amdgcn_mfma_f32_16x16x32_f16(wr[0][0], b0, zero4, 0, 0, 0);
            f32x4 a1 = __builtin_amdgcn_mfma_f32_16x16x32_f16(wr[1][0], b0, zero4, 0, 0, 0);
            #pragma unroll
            for (int kc = 1; kc < 4; ++kc) {
                f16x8 bh = *(const f16x8*)(cb + hro[kc]);
                a0 = __builtin_amdgcn_mfma_f32_16x16x32_f16(wr[0][kc], bh, a0, 0, 0, 0);
                a1 = __builtin_amdgcn_mfma_f32_16x16x32_f16(wr[1][kc], bh, a1, 0, 0, 0);
            }
            a0 = __builtin_amdgcn_mfma_f32_16x16x32_f16(wr[0][4], bx, a0, 0, 0, 0);
            a1 = __builtin_amdgcn_mfma_f32_16x16x32_f16(wr[1][4], bx, a1, 0, 0, 0);

            // cell update: acc[idx] = (i,f,g,o) of unit w*8+q*2+gs, sample ns*16+cl
            float i0 = fsig(a0[0]), f0 = fsig(a0[1]), g0 = ftanh(a0[2]), o0 = fsig(a0[3]);
            float cn0 = f0 * creg[0][ns] + i0 * g0;
            creg[0][ns] = cn0;
            float h0 = o0 * ftanh(cn0);
            float i1 = fsig(a1[0]), f1 = fsig(a1[1]), g1 = ftanh(a1[2]), o1 = fsig(a1[3]);
            float cn1 = f1 * creg[1][ns] + i1 * g1;
            creg[1][ns] = cn1;
            float h1 = o1 * ftanh(cn1);
            union { f16 h[2]; uint32_t u; } pk;
            pk.h[0] = (f16)h0; pk.h[1] = (f16)h1;
            *(uint32_t*)(state + nxtoff + ns * 4096 + hwo) = pk.u;
        }
        __syncthreads();   // writes to nxt visible; cur reads done
    }

    // decoder weights + decoder-only registers (loaded late)
    load_frags(dWih, dWhh, dbih, dbhh, w, q, cl, wr);
    float lw0[2], lw1[2];
    #pragma unroll
    for (int gs = 0; gs < 2; ++gs) {
        lw0[gs] = linW[w * 8 + q * 2 + gs];
        lw1[gs] = linW[128 + w * 8 + q * 2 + gs];
    }
    float sc0 = 0.f, sc1 = 0.f, sc2 = 0.f, lb0 = 0.f, lb1 = 0.f;
    if (tid < SAMP) {
        const float* xr = x + (size_t)(s0 + tid) * (TT * II) + 49 * II;
        sc0 = xr[2]; sc1 = xr[3]; sc2 = xr[4];
        lb0 = linB[0]; lb1 = linB[1];
    }

    // ===================== decoder =====================
    // after 50 encoder steps h lives in buf0; dec_in0 = x[49] row already in xstage
    #pragma unroll 1
    for (int td = 0; td < PRED; ++td) {
        const int curoff = (td & 1) << 14;
        const int nxtoff = curoff ^ 16384;
        const int xslot  = (td == 0) ? 49 : (50 + (td & 1));
        #pragma unroll
        for (int ns = 0; ns < NSB; ++ns) {
            const unsigned char* cb = state + curoff + ns * 4096;
            f16x8 bx = *(const f16x8*)(xstage + (xslot * SAMP + ns * 16 + cl) * 8);
            f16x8 b0 = *(const f16x8*)(cb + hro[0]);
            f32x4 a0 = __builtin_amdgcn_mfma_f32_16x16x32_f16(wr[0][0], b0, zero4, 0, 0, 0);
            f32x4 a1 = __builtin_amdgcn_mfma_f32_16x16x32_f16(wr[1][0], b0, zero4, 0, 0, 0);
            #pragma unroll
            for (int kc = 1; kc < 4; ++kc) {
                f16x8 bh = *(const f16x8*)(cb + hro[kc]);
                a0 = __builtin_amdgcn_mfma_f32_16x16x32_f16(wr[0][kc], bh, a0, 0, 0, 0);
                a1 = __builtin_amdgcn_mfma_f32_16x16x32_f16(wr[1][kc], bh, a1, 0, 0, 0);
            }
            a0 = __builtin_amdgcn_mfma_f32_16x16x32_f16(wr[0][4], bx, a0, 0, 0, 0);
            a1 = __builtin_amdgcn_mfma_f32_16x16x32_f16(wr[1][4], bx, a1, 0, 0, 0);

            float i0 = fsig(a0[0]), f0 = fsig(a0[1]), g0 = ftanh(a0[2]), o0 = fsig(a0[3]);
            float cn0 = f0 * creg[0][ns] + i0 * g0;
            creg[0][ns] = cn0;
            float h0 = o0 * ftanh(cn0);
            float i1 = fsig(a1[0]), f1 = fsig(a1[1]), g1 = ftanh(a1[2]), o1 = fsig(a1[3]);
            float cn1 = f1 * creg[1][ns] + i1 * g1;
            creg[1][ns] = cn1;
            float h1 = o1 * ftanh(cn1);
            union { f16 h[2]; uint32_t u; } pk;
            pk.h[0] = (f16)h0; pk.h[1] = (f16)h1;
            *(uint32_t*)(state + nxtoff + ns * 4096 + hwo) = pk.u;

            // pred partials: this lane covers units w*8+q*2+{0,1}
            float p0 = h0 * lw0[0] + h1 * lw0[1];
            float p1 = h0 * lw1[0] + h1 * lw1[1];
            p0 += __shfl_xor(p0, 16); p0 += __shfl_xor(p0, 32);
            p1 += __shfl_xor(p1, 16); p1 += __shfl_xor(p1, 32);
            if (q == 0) {
                predpart[w][ns * 16 + cl][0] = p0;
                predpart[w][ns * 16 + cl][1] = p1;
            }
        }
        __syncthreads();   // A: predpart ready, state reads done
        if (tid < SAMP) {
            float a0 = lb0, a1 = lb1;
            #pragma unroll
            for (int ww = 0; ww < 16; ++ww) {
                a0 += predpart[ww][tid][0];
                a1 += predpart[ww][tid][1];
            }
            float2 o2; o2.x = a0; o2.y = a1;
            *(float2*)(out + (size_t)(s0 + tid) * (PRED * 2) + td * 2) = o2;
            union { f16 h[8]; uint4 u; } pk;
            pk.h[0] = (f16)a0;  pk.h[1] = (f16)a1;
            pk.h[2] = (f16)sc0; pk.h[3] = (f16)sc1; pk.h[4] = (f16)sc2;
            pk.h[5] = (f16)1.f; pk.h[6] = (f16)0.f; pk.h[7] = (f16)0.f;
            int ws = 50 + ((td + 1) & 1);
            *(uint4*)(xstage + (ws * SAMP + tid) * 8) = pk.u;   // next dec_in
        }
        __syncthreads();   // B: dec_in visible
    }
}

extern "C" void kernel_launch(void* const* d_in, const int* in_sizes, int n_in,
                              void* d_out, int out_size, void* d_ws, size_t ws_size,
                              hipStream_t stream) {
    (void)in_sizes; (void)n_in; (void)out_size; (void)d_ws; (void)ws_size;
    const float* x    = (const float*)d_in[0];
    const float* eWih = (const float*)d_in[1];
    const float* eWhh = (const float*)d_in[2];
    const float* ebih = (const float*)d_in[3];
    const float* ebhh = (const float*)d_in[4];
    const float* dWih = (const float*)d_in[5];
    const float* dWhh = (const float*)d_in[6];
    const float* dbih = (const float*)d_in[7];
    const float* dbhh = (const float*)d_in[8];
    const float* linW = (const float*)d_in[9];
    const float* linB = (const float*)d_in[10];

    lstm_kernel<<<256, 1024, 0, stream>>>(x, eWih, eWhh, ebih, ebhh,
                                          dWih, dWhh, dbih, dbhh,
                                          linW, linB, (float*)d_out);
}